// Round 12
// baseline (353.907 us; speedup 1.0000x reference)
//
#include <hip/hip_runtime.h>

#define NV 6144
#define DV 64

using short8 = __attribute__((ext_vector_type(8))) short;
using f32x4  = __attribute__((ext_vector_type(4))) float;

static __device__ __forceinline__ unsigned short f2bf(float x){
  unsigned u = __float_as_uint(x);
  u += 0x7FFFu + ((u >> 16) & 1u);      // RNE
  return (unsigned short)(u >> 16);
}

// ---------------- projections: hq = x@Wq (f32 out + bf16 qb), kb = bf16(x@Wk),
// xbT[d][i] = bf16(x@Wa) transposed. Also zeroes lsum (and adjs in phase 1).
template<int FIN>
__global__ __launch_bounds__(256) void k_proj(
    const float* __restrict__ x, const float* __restrict__ Wq,
    const float* __restrict__ Wk, const float* __restrict__ Wa,
    float* __restrict__ hq_out, unsigned short* __restrict__ qb,
    unsigned short* __restrict__ kb, unsigned short* __restrict__ xbT,
    float* __restrict__ lsum, float* __restrict__ adjs)
{
  __shared__ float xr[FIN];
  int i = blockIdx.x, t = threadIdx.x;
  for (int f = t; f < FIN; f += 256) xr[f] = x[(size_t)i*FIN + f];
  if (t == 192) lsum[i] = 0.f;
  if (FIN == 256 && t == 193) adjs[i] = 0.f;
  __syncthreads();
  if (t < 192){
    int w = t >> 6, d = t & 63;
    const float* W = (w == 0) ? Wq : ((w == 1) ? Wk : Wa);
    float acc = 0.f;
    #pragma unroll 8
    for (int f = 0; f < FIN; ++f) acc = fmaf(xr[f], W[f*DV + d], acc);
    size_t o = (size_t)i*DV + d;
    if (w == 0){ hq_out[o] = acc; qb[o] = f2bf(acc); }
    else if (w == 1) kb[o] = f2bf(acc);
    else xbT[(size_t)d*NV + i] = f2bf(acc);
  }
}

// ---------------- pass 1: lsum[i] = sum_j exp((qb@kb^T)*0.125)  (no-max softmax)
// grid: (48,48); block 256 = 4 waves (2x2 of 64x64); tile 128x128.
__global__ __launch_bounds__(256) void k_scores_l(
    const unsigned short* __restrict__ qb, const unsigned short* __restrict__ kb,
    float* __restrict__ lsum)
{
  __shared__ unsigned short qs[128][72];   // +8 ushort pad
  __shared__ unsigned short ks[128][72];
  int t = threadIdx.x;
  int row0 = blockIdx.x * 128, col0 = blockIdx.y * 128;
  #pragma unroll
  for (int p = 0; p < 4; ++p){
    int idx = t + p*256;
    int r = idx >> 3, c = (idx & 7) * 8;
    *(uint4*)&qs[r][c] = *(const uint4*)&qb[(size_t)(row0 + r)*DV + c];
    *(uint4*)&ks[r][c] = *(const uint4*)&kb[(size_t)(col0 + r)*DV + c];
  }
  __syncthreads();
  int lane = t & 63, w = t >> 6;
  int wi = (w >> 1) * 64, wj = (w & 1) * 64;
  int m = lane & 15, g = lane >> 4;
  f32x4 acc[4][4];
  #pragma unroll
  for (int r = 0; r < 4; ++r)
    #pragma unroll
    for (int c = 0; c < 4; ++c)
      acc[r][c] = (f32x4){0.f, 0.f, 0.f, 0.f};
  #pragma unroll
  for (int kk = 0; kk < 2; ++kk){
    short8 a[4], b[4];
    #pragma unroll
    for (int r = 0; r < 4; ++r)
      a[r] = *(const short8*)&qs[wi + r*16 + m][kk*32 + g*8];
    #pragma unroll
    for (int c = 0; c < 4; ++c)
      b[c] = *(const short8*)&ks[wj + c*16 + m][kk*32 + g*8];
    #pragma unroll
    for (int r = 0; r < 4; ++r)
      #pragma unroll
      for (int c = 0; c < 4; ++c)
        acc[r][c] = __builtin_amdgcn_mfma_f32_16x16x32_bf16(a[r], b[c], acc[r][c], 0, 0, 0);
  }
  #pragma unroll
  for (int r = 0; r < 4; ++r){
    float rs[4] = {0.f, 0.f, 0.f, 0.f};
    #pragma unroll
    for (int c = 0; c < 4; ++c)
      #pragma unroll
      for (int v = 0; v < 4; ++v)
        rs[v] += __expf(acc[r][c][v] * 0.125f);
    #pragma unroll
    for (int v = 0; v < 4; ++v){
      float s = rs[v];
      s += __shfl_xor(s, 1);
      s += __shfl_xor(s, 2);
      s += __shfl_xor(s, 4);
      s += __shfl_xor(s, 8);
      if (m == 0) atomicAdd(&lsum[row0 + wi + r*16 + g*4 + v], s);
    }
  }
}

// ---------------- pass 2 (fused): recompute S chunk, R = a*base+(1-a)*e/l,
// write R f32 (output), R bf16 -> LDS, agg-MFMA into hpart[split].
// grid: 96 row-tiles * 16 k-splits; block 256 = 4 waves; 64 rows x 384 k.
// LDS = ks+rs+xt = 53,248 B -> 3 blocks/CU (Q frags + linv in registers).
template<int PHASE1>
__global__ __launch_bounds__(256) void k_fused(
    const unsigned short* __restrict__ qb, const unsigned short* __restrict__ kb,
    const unsigned short* __restrict__ xbT, const float* __restrict__ lsum,
    const float* __restrict__ base, float* __restrict__ Rout,
    float* __restrict__ hpart, float* __restrict__ adjs, float aconst)
{
  __shared__ unsigned short ks[128][72];   // k rows for current chunk
  __shared__ unsigned short rs[64][136];   // R bf16 tile (agg A-operand)
  __shared__ unsigned short xt[64][136];   // xbT chunk (agg B-operand)

  int t = threadIdx.x;
  int tile = blockIdx.x >> 4, split = blockIdx.x & 15;
  int row0 = tile * 64, k0 = split * 384;
  int lane = t & 63, w = t >> 6;
  int m = lane & 15, g = lane >> 4;

  int srow = (w >> 1) * 32;                // scores wave role
  int scol = (w & 1) * 64;

  // Q A-fragments in registers (qb is L2-resident), reused all 3 chunks
  short8 aq[2][2];
  #pragma unroll
  for (int r = 0; r < 2; ++r)
    #pragma unroll
    for (int kk = 0; kk < 2; ++kk)
      aq[r][kk] = *(const short8*)&qb[(size_t)(row0 + srow + r*16 + m)*DV + kk*32 + g*8];

  // per-thread softmax scale factors for the 8 owned rows
  float linv_r[2][4];
  #pragma unroll
  for (int r = 0; r < 2; ++r)
    #pragma unroll
    for (int v = 0; v < 4; ++v)
      linv_r[r][v] = (1.0f - aconst) / lsum[row0 + srow + r*16 + g*4 + v];

  float asum[2][4];
  if (PHASE1){
    #pragma unroll
    for (int r = 0; r < 2; ++r)
      #pragma unroll
      for (int v = 0; v < 4; ++v) asum[r][v] = 0.f;
  }
  f32x4 acc_g[4];
  #pragma unroll
  for (int c = 0; c < 4; ++c) acc_g[c] = (f32x4){0.f, 0.f, 0.f, 0.f};

  for (int kc = 0; kc < 3; ++kc){
    int c0 = k0 + kc*128;
    __syncthreads();                       // prev agg reads of ks/xt/rs done
    #pragma unroll
    for (int p = 0; p < 4; ++p){           // ks: 128 rows x 8 uint4
      int idx = t + p*256;
      int r = idx >> 3, c = (idx & 7)*8;
      *(uint4*)&ks[r][c] = *(const uint4*)&kb[(size_t)(c0 + r)*DV + c];
    }
    #pragma unroll
    for (int p = 0; p < 4; ++p){           // xt: 64 d x 16 uint4
      int idx = t + p*256;
      int d = idx >> 4, c = (idx & 15)*8;
      *(uint4*)&xt[d][c] = *(const uint4*)&xbT[(size_t)d*NV + c0 + c];
    }
    __syncthreads();
    // scores MFMA: this wave's 32 rows x 64 cols
    f32x4 acc_s[2][4];
    #pragma unroll
    for (int r = 0; r < 2; ++r)
      #pragma unroll
      for (int c = 0; c < 4; ++c) acc_s[r][c] = (f32x4){0.f, 0.f, 0.f, 0.f};
    #pragma unroll
    for (int kk = 0; kk < 2; ++kk){
      short8 b[4];
      #pragma unroll
      for (int c = 0; c < 4; ++c)
        b[c] = *(const short8*)&ks[scol + c*16 + m][kk*32 + g*8];
      #pragma unroll
      for (int r = 0; r < 2; ++r)
        #pragma unroll
        for (int c = 0; c < 4; ++c)
          acc_s[r][c] = __builtin_amdgcn_mfma_f32_16x16x32_bf16(aq[r][kk], b[c], acc_s[r][c], 0, 0, 0);
    }
    // blend: e, R write (f32 out), rs write (bf16), adjsum partials
    #pragma unroll
    for (int r = 0; r < 2; ++r){
      #pragma unroll
      for (int c = 0; c < 4; ++c){
        int col_l = scol + c*16 + m;
        size_t gcol = (size_t)c0 + col_l;
        #pragma unroll
        for (int v = 0; v < 4; ++v){
          int row_l = srow + r*16 + g*4 + v;
          size_t goff = (size_t)(row0 + row_l)*NV + gcol;
          float e = __expf(acc_s[r][c][v] * 0.125f);
          float bv = base[goff];
          float rv = fmaf(aconst, bv, e * linv_r[r][v]);
          Rout[goff] = rv;
          rs[row_l][col_l] = f2bf(rv);
          if (PHASE1) asum[r][v] += bv;
        }
      }
    }
    __syncthreads();
    // agg MFMA: wave w owns rows w*16..w*16+15; full d=64
    #pragma unroll
    for (int kk = 0; kk < 4; ++kk){
      short8 a = *(const short8*)&rs[w*16 + m][kk*32 + g*8];
      short8 b[4];
      #pragma unroll
      for (int c = 0; c < 4; ++c)
        b[c] = *(const short8*)&xt[c*16 + m][kk*32 + g*8];
      #pragma unroll
      for (int c = 0; c < 4; ++c)
        acc_g[c] = __builtin_amdgcn_mfma_f32_16x16x32_bf16(a, b[c], acc_g[c], 0, 0, 0);
    }
  }
  // hpart epilogue (deterministic)
  float* hp = hpart + (size_t)split * NV * DV;
  #pragma unroll
  for (int c = 0; c < 4; ++c){
    int d = c*16 + m;
    #pragma unroll
    for (int v = 0; v < 4; ++v){
      int row = row0 + w*16 + g*4 + v;
      hp[(size_t)row*DV + d] = acc_g[c][v];
    }
  }
  if (PHASE1){
    #pragma unroll
    for (int r = 0; r < 2; ++r)
      #pragma unroll
      for (int v = 0; v < 4; ++v){
        float s = asum[r][v];
        s += __shfl_xor(s, 1);
        s += __shfl_xor(s, 2);
        s += __shfl_xor(s, 4);
        s += __shfl_xor(s, 8);
        if (m == 0) atomicAdd(&adjs[row0 + srow + r*16 + g*4 + v], s);
      }
  }
}

// ---------------- finalize phase 1: h1 = relu(sum(hpart)/deg1) + q1
__global__ __launch_bounds__(256) void k_fin1(
    const float* __restrict__ hpart, const float* __restrict__ adjsum,
    const float* __restrict__ q1, float* __restrict__ h1)
{
  int idx = blockIdx.x*256 + threadIdx.x;
  int i = idx >> 6;
  float hv = 0.f;
  #pragma unroll
  for (int p = 0; p < 16; ++p) hv += hpart[(size_t)p*NV*DV + idx];
  float deg = fmaxf(fmaf(0.8f, adjsum[i], 0.2f), 1e-12f);
  h1[idx] = fmaxf(hv/deg, 0.f) + q1[idx];
}

// ---------------- finalize phase 2: h2 = sum(hpart)/deg2 + q2; log_softmax
__global__ __launch_bounds__(64) void k_fin2(
    const float* __restrict__ hpart, const float* __restrict__ adjsum,
    const float* __restrict__ q2, float* __restrict__ out0)
{
  int i = blockIdx.x, d = threadIdx.x;
  int idx = i*64 + d;
  float hv = 0.f;
  #pragma unroll
  for (int p = 0; p < 16; ++p) hv += hpart[(size_t)p*NV*DV + idx];
  float deg1 = fmaxf(fmaf(0.8f, adjsum[i], 0.2f), 1e-12f);
  float deg2 = fmaxf(fmaf(0.9f, deg1, 0.1f), 1e-12f);
  float v = hv/deg2 + q2[idx];
  float mm = v;
  #pragma unroll
  for (int mask = 32; mask; mask >>= 1) mm = fmaxf(mm, __shfl_xor(mm, mask));
  float ex = __expf(v - mm);
  #pragma unroll
  for (int mask = 32; mask; mask >>= 1) ex += __shfl_xor(ex, mask);
  out0[idx] = v - mm - __logf(ex);
}

extern "C" void kernel_launch(void* const* d_in, const int* in_sizes, int n_in,
                              void* d_out, int out_size, void* d_ws, size_t ws_size,
                              hipStream_t stream) {
  const float* adj  = (const float*)d_in[0];
  const float* feat = (const float*)d_in[1];
  const float* Wq1  = (const float*)d_in[2];
  const float* Wk1  = (const float*)d_in[3];
  const float* Wa1  = (const float*)d_in[4];
  const float* Wq2  = (const float*)d_in[5];
  const float* Wk2  = (const float*)d_in[6];
  const float* Wa2  = (const float*)d_in[7];

  float* out   = (float*)d_out;
  float* o_ls  = out;                        // [N,64] log_softmax(h2)
  float* o_hq1 = out + (size_t)NV*DV;        // [N,64]
  float* o_R1  = o_hq1 + (size_t)NV*DV;      // [N,N]
  float* o_hq2 = o_R1 + (size_t)NV*NV;       // [N,64]
  float* o_R2  = o_hq2 + (size_t)NV*DV;      // [N,N]

  const size_t ND = (size_t)NV*DV;           // 393216

  // d_ws (~1.2 GB); we use ~33 MB.
  float* Wf   = (float*)d_ws;
  float* lsum = Wf;                          // [N]
  float* adjs = lsum + NV;                   // [N]
  float* h1   = adjs + NV;                   // [N,64]
  float* hpart= h1 + ND;                     // [16][N][64]
  unsigned short* qb  = (unsigned short*)(hpart + 16*ND);  // [N,64] bf16
  unsigned short* kb  = qb + ND;                           // [N,64] bf16
  unsigned short* xbT = kb + ND;                           // [64][N] bf16

  // phase 1
  k_proj<256><<<NV, 256, 0, stream>>>(feat, Wq1, Wk1, Wa1, o_hq1, qb, kb, xbT, lsum, adjs);
  k_scores_l<<<dim3(48,48), 256, 0, stream>>>(qb, kb, lsum);
  k_fused<1><<<96*16, 256, 0, stream>>>(qb, kb, xbT, lsum, adj, o_R1, hpart, adjs, 0.8f);
  k_fin1<<<(NV*DV)/256, 256, 0, stream>>>(hpart, adjs, o_hq1, h1);
  // phase 2
  k_proj<64><<<NV, 256, 0, stream>>>(h1, Wq2, Wk2, Wa2, o_hq2, qb, kb, xbT, lsum, nullptr);
  k_scores_l<<<dim3(48,48), 256, 0, stream>>>(qb, kb, lsum);
  k_fused<0><<<96*16, 256, 0, stream>>>(qb, kb, xbT, lsum, o_R1, o_R2, hpart, nullptr, 0.9f);
  k_fin2<<<NV, 64, 0, stream>>>(hpart, adjs, o_hq2, o_ls);
}

// Round 13
// 247.364 us; speedup vs baseline: 1.4307x; 1.4307x over previous
//
#include <hip/hip_runtime.h>

#define NV 6144
#define DV 64

using short8 = __attribute__((ext_vector_type(8))) short;
using f32x4  = __attribute__((ext_vector_type(4))) float;

static __device__ __forceinline__ unsigned short f2bf(float x){
  unsigned u = __float_as_uint(x);
  u += 0x7FFFu + ((u >> 16) & 1u);      // RNE
  return (unsigned short)(u >> 16);
}

// ---------------- projections: hq = x@Wq (f32 out + bf16 qb), kb = bf16(x@Wk),
// xbT[d][i] = bf16(x@Wa) transposed. Also zeroes lsum (and adjs in phase 1).
template<int FIN>
__global__ __launch_bounds__(256) void k_proj(
    const float* __restrict__ x, const float* __restrict__ Wq,
    const float* __restrict__ Wk, const float* __restrict__ Wa,
    float* __restrict__ hq_out, unsigned short* __restrict__ qb,
    unsigned short* __restrict__ kb, unsigned short* __restrict__ xbT,
    float* __restrict__ lsum, float* __restrict__ adjs)
{
  __shared__ float xr[FIN];
  int i = blockIdx.x, t = threadIdx.x;
  for (int f = t; f < FIN; f += 256) xr[f] = x[(size_t)i*FIN + f];
  if (t == 192) lsum[i] = 0.f;
  if (FIN == 256 && t == 193) adjs[i] = 0.f;
  __syncthreads();
  if (t < 192){
    int w = t >> 6, d = t & 63;
    const float* W = (w == 0) ? Wq : ((w == 1) ? Wk : Wa);
    float acc = 0.f;
    #pragma unroll 8
    for (int f = 0; f < FIN; ++f) acc = fmaf(xr[f], W[f*DV + d], acc);
    size_t o = (size_t)i*DV + d;
    if (w == 0){ hq_out[o] = acc; qb[o] = f2bf(acc); }
    else if (w == 1) kb[o] = f2bf(acc);
    else xbT[(size_t)d*NV + i] = f2bf(acc);
  }
}

// ---------------- pass 1: lsum[i] = sum_j exp((qb@kb^T)*0.125)  (no-max softmax)
// grid: (48,48); block 256 = 4 waves (2x2 of 64x64); tile 128x128.
__global__ __launch_bounds__(256) void k_scores_l(
    const unsigned short* __restrict__ qb, const unsigned short* __restrict__ kb,
    float* __restrict__ lsum)
{
  __shared__ unsigned short qs[128][72];   // +8 ushort pad
  __shared__ unsigned short ks[128][72];
  int t = threadIdx.x;
  int row0 = blockIdx.x * 128, col0 = blockIdx.y * 128;
  #pragma unroll
  for (int p = 0; p < 4; ++p){
    int idx = t + p*256;
    int r = idx >> 3, c = (idx & 7) * 8;
    *(uint4*)&qs[r][c] = *(const uint4*)&qb[(size_t)(row0 + r)*DV + c];
    *(uint4*)&ks[r][c] = *(const uint4*)&kb[(size_t)(col0 + r)*DV + c];
  }
  __syncthreads();
  int lane = t & 63, w = t >> 6;
  int wi = (w >> 1) * 64, wj = (w & 1) * 64;
  int m = lane & 15, g = lane >> 4;
  f32x4 acc[4][4];
  #pragma unroll
  for (int r = 0; r < 4; ++r)
    #pragma unroll
    for (int c = 0; c < 4; ++c)
      acc[r][c] = (f32x4){0.f, 0.f, 0.f, 0.f};
  #pragma unroll
  for (int kk = 0; kk < 2; ++kk){
    short8 a[4], b[4];
    #pragma unroll
    for (int r = 0; r < 4; ++r)
      a[r] = *(const short8*)&qs[wi + r*16 + m][kk*32 + g*8];
    #pragma unroll
    for (int c = 0; c < 4; ++c)
      b[c] = *(const short8*)&ks[wj + c*16 + m][kk*32 + g*8];
    #pragma unroll
    for (int r = 0; r < 4; ++r)
      #pragma unroll
      for (int c = 0; c < 4; ++c)
        acc[r][c] = __builtin_amdgcn_mfma_f32_16x16x32_bf16(a[r], b[c], acc[r][c], 0, 0, 0);
  }
  #pragma unroll
  for (int r = 0; r < 4; ++r){
    float rs[4] = {0.f, 0.f, 0.f, 0.f};
    #pragma unroll
    for (int c = 0; c < 4; ++c)
      #pragma unroll
      for (int v = 0; v < 4; ++v)
        rs[v] += __expf(acc[r][c][v] * 0.125f);
    #pragma unroll
    for (int v = 0; v < 4; ++v){
      float s = rs[v];
      s += __shfl_xor(s, 1);
      s += __shfl_xor(s, 2);
      s += __shfl_xor(s, 4);
      s += __shfl_xor(s, 8);
      if (m == 0) atomicAdd(&lsum[row0 + wi + r*16 + g*4 + v], s);
    }
  }
}

// ---------------- pass 2 (fused): recompute S chunk, R = a*base+(1-a)*e/l,
// write R f32 (output), R bf16 -> LDS, agg-MFMA into hpart[split].
// grid: 96 row-tiles * 16 k-splits; block 256 = 4 waves; 64 rows x 384 k.
// (round-8/11 structure — verified 254 us twice; do not restructure)
template<int PHASE1>
__global__ __launch_bounds__(256) void k_fused(
    const unsigned short* __restrict__ qb, const unsigned short* __restrict__ kb,
    const unsigned short* __restrict__ xbT, const float* __restrict__ lsum,
    const float* __restrict__ base, float* __restrict__ Rout,
    float* __restrict__ hpart, float* __restrict__ adjs, float aconst)
{
  __shared__ unsigned short qs[64][72];    // q rows (persistent)
  __shared__ unsigned short ks[128][72];   // k rows for current chunk
  __shared__ unsigned short rs[64][136];   // R bf16 tile (agg A-operand)
  __shared__ unsigned short xt[64][136];   // xbT chunk (agg B-operand)
  __shared__ float linv[64];

  int t = threadIdx.x;
  int tile = blockIdx.x >> 4, split = blockIdx.x & 15;
  int row0 = tile * 64, k0 = split * 384;
  int lane = t & 63, w = t >> 6;
  int m = lane & 15, g = lane >> 4;

  #pragma unroll
  for (int p = 0; p < 2; ++p){             // qs: 64 rows x 8 uint4
    int idx = t + p*256;
    int r = idx >> 3, c = (idx & 7)*8;
    *(uint4*)&qs[r][c] = *(const uint4*)&qb[(size_t)(row0 + r)*DV + c];
  }
  if (t < 64) linv[t] = (1.0f - aconst) / lsum[row0 + t];

  int srow = (w >> 1) * 32;                // scores wave role
  int scol = (w & 1) * 64;
  float asum[2][4];
  if (PHASE1){
    #pragma unroll
    for (int r = 0; r < 2; ++r)
      #pragma unroll
      for (int v = 0; v < 4; ++v) asum[r][v] = 0.f;
  }
  f32x4 acc_g[4];
  #pragma unroll
  for (int c = 0; c < 4; ++c) acc_g[c] = (f32x4){0.f, 0.f, 0.f, 0.f};

  for (int kc = 0; kc < 3; ++kc){
    int c0 = k0 + kc*128;
    __syncthreads();                       // prev agg reads of ks/xt/rs done
    #pragma unroll
    for (int p = 0; p < 4; ++p){           // ks: 128 rows x 8 uint4
      int idx = t + p*256;
      int r = idx >> 3, c = (idx & 7)*8;
      *(uint4*)&ks[r][c] = *(const uint4*)&kb[(size_t)(c0 + r)*DV + c];
    }
    #pragma unroll
    for (int p = 0; p < 4; ++p){           // xt: 64 d x 16 uint4
      int idx = t + p*256;
      int d = idx >> 4, c = (idx & 15)*8;
      *(uint4*)&xt[d][c] = *(const uint4*)&xbT[(size_t)d*NV + c0 + c];
    }
    __syncthreads();
    // scores MFMA: this wave's 32 rows x 64 cols
    f32x4 acc_s[2][4];
    #pragma unroll
    for (int r = 0; r < 2; ++r)
      #pragma unroll
      for (int c = 0; c < 4; ++c) acc_s[r][c] = (f32x4){0.f, 0.f, 0.f, 0.f};
    #pragma unroll
    for (int kk = 0; kk < 2; ++kk){
      short8 a[2], b[4];
      #pragma unroll
      for (int r = 0; r < 2; ++r)
        a[r] = *(const short8*)&qs[srow + r*16 + m][kk*32 + g*8];
      #pragma unroll
      for (int c = 0; c < 4; ++c)
        b[c] = *(const short8*)&ks[scol + c*16 + m][kk*32 + g*8];
      #pragma unroll
      for (int r = 0; r < 2; ++r)
        #pragma unroll
        for (int c = 0; c < 4; ++c)
          acc_s[r][c] = __builtin_amdgcn_mfma_f32_16x16x32_bf16(a[r], b[c], acc_s[r][c], 0, 0, 0);
    }
    // blend: e, R write (f32 out), rs write (bf16), adjsum partials
    #pragma unroll
    for (int r = 0; r < 2; ++r){
      #pragma unroll
      for (int c = 0; c < 4; ++c){
        int col_l = scol + c*16 + m;
        size_t gcol = (size_t)c0 + col_l;
        #pragma unroll
        for (int v = 0; v < 4; ++v){
          int row_l = srow + r*16 + g*4 + v;
          size_t goff = (size_t)(row0 + row_l)*NV + gcol;
          float e = __expf(acc_s[r][c][v] * 0.125f);
          float bv = base[goff];
          float rv = fmaf(aconst, bv, e * linv[row_l]);
          Rout[goff] = rv;
          rs[row_l][col_l] = f2bf(rv);
          if (PHASE1) asum[r][v] += bv;
        }
      }
    }
    __syncthreads();
    // agg MFMA: wave w owns rows w*16..w*16+15; full d=64
    #pragma unroll
    for (int kk = 0; kk < 4; ++kk){
      short8 a = *(const short8*)&rs[w*16 + m][kk*32 + g*8];
      short8 b[4];
      #pragma unroll
      for (int c = 0; c < 4; ++c)
        b[c] = *(const short8*)&xt[c*16 + m][kk*32 + g*8];
      #pragma unroll
      for (int c = 0; c < 4; ++c)
        acc_g[c] = __builtin_amdgcn_mfma_f32_16x16x32_bf16(a, b[c], acc_g[c], 0, 0, 0);
    }
  }
  // hpart epilogue (deterministic)
  float* hp = hpart + (size_t)split * NV * DV;
  #pragma unroll
  for (int c = 0; c < 4; ++c){
    int d = c*16 + m;
    #pragma unroll
    for (int v = 0; v < 4; ++v){
      int row = row0 + w*16 + g*4 + v;
      hp[(size_t)row*DV + d] = acc_g[c][v];
    }
  }
  if (PHASE1){
    #pragma unroll
    for (int r = 0; r < 2; ++r)
      #pragma unroll
      for (int v = 0; v < 4; ++v){
        float s = asum[r][v];
        s += __shfl_xor(s, 1);
        s += __shfl_xor(s, 2);
        s += __shfl_xor(s, 4);
        s += __shfl_xor(s, 8);
        if (m == 0) atomicAdd(&adjs[row0 + srow + r*16 + g*4 + v], s);
      }
  }
}

// ---------------- finalize phase 1: h1 = relu(sum(hpart)/deg1) + q1
__global__ __launch_bounds__(256) void k_fin1(
    const float* __restrict__ hpart, const float* __restrict__ adjsum,
    const float* __restrict__ q1, float* __restrict__ h1)
{
  int idx = blockIdx.x*256 + threadIdx.x;
  int i = idx >> 6;
  float hv = 0.f;
  #pragma unroll
  for (int p = 0; p < 16; ++p) hv += hpart[(size_t)p*NV*DV + idx];
  float deg = fmaxf(fmaf(0.8f, adjsum[i], 0.2f), 1e-12f);
  h1[idx] = fmaxf(hv/deg, 0.f) + q1[idx];
}

// ---------------- finalize phase 2: h2 = sum(hpart)/deg2 + q2; log_softmax
__global__ __launch_bounds__(64) void k_fin2(
    const float* __restrict__ hpart, const float* __restrict__ adjsum,
    const float* __restrict__ q2, float* __restrict__ out0)
{
  int i = blockIdx.x, d = threadIdx.x;
  int idx = i*64 + d;
  float hv = 0.f;
  #pragma unroll
  for (int p = 0; p < 16; ++p) hv += hpart[(size_t)p*NV*DV + idx];
  float deg1 = fmaxf(fmaf(0.8f, adjsum[i], 0.2f), 1e-12f);
  float deg2 = fmaxf(fmaf(0.9f, deg1, 0.1f), 1e-12f);
  float v = hv/deg2 + q2[idx];
  float mm = v;
  #pragma unroll
  for (int mask = 32; mask; mask >>= 1) mm = fmaxf(mm, __shfl_xor(mm, mask));
  float ex = __expf(v - mm);
  #pragma unroll
  for (int mask = 32; mask; mask >>= 1) ex += __shfl_xor(ex, mask);
  out0[idx] = v - mm - __logf(ex);
}

extern "C" void kernel_launch(void* const* d_in, const int* in_sizes, int n_in,
                              void* d_out, int out_size, void* d_ws, size_t ws_size,
                              hipStream_t stream) {
  const float* adj  = (const float*)d_in[0];
  const float* feat = (const float*)d_in[1];
  const float* Wq1  = (const float*)d_in[2];
  const float* Wk1  = (const float*)d_in[3];
  const float* Wa1  = (const float*)d_in[4];
  const float* Wq2  = (const float*)d_in[5];
  const float* Wk2  = (const float*)d_in[6];
  const float* Wa2  = (const float*)d_in[7];

  float* out   = (float*)d_out;
  float* o_ls  = out;                        // [N,64] log_softmax(h2)
  float* o_hq1 = out + (size_t)NV*DV;        // [N,64]
  float* o_R1  = o_hq1 + (size_t)NV*DV;      // [N,N]
  float* o_hq2 = o_R1 + (size_t)NV*NV;       // [N,64]
  float* o_R2  = o_hq2 + (size_t)NV*DV;      // [N,N]

  const size_t ND = (size_t)NV*DV;           // 393216

  // d_ws (~1.2 GB); we use ~33 MB.
  float* Wf   = (float*)d_ws;
  float* lsum = Wf;                          // [N]
  float* adjs = lsum + NV;                   // [N]
  float* h1   = adjs + NV;                   // [N,64]
  float* hpart= h1 + ND;                     // [16][N][64]
  unsigned short* qb  = (unsigned short*)(hpart + 16*ND);  // [N,64] bf16
  unsigned short* kb  = qb + ND;                           // [N,64] bf16
  unsigned short* xbT = kb + ND;                           // [64][N] bf16

  // phase 1
  k_proj<256><<<NV, 256, 0, stream>>>(feat, Wq1, Wk1, Wa1, o_hq1, qb, kb, xbT, lsum, adjs);
  k_scores_l<<<dim3(48,48), 256, 0, stream>>>(qb, kb, lsum);
  k_fused<1><<<96*16, 256, 0, stream>>>(qb, kb, xbT, lsum, adj, o_R1, hpart, adjs, 0.8f);
  k_fin1<<<(NV*DV)/256, 256, 0, stream>>>(hpart, adjs, o_hq1, h1);
  // phase 2
  k_proj<64><<<NV, 256, 0, stream>>>(h1, Wq2, Wk2, Wa2, o_hq2, qb, kb, xbT, lsum, nullptr);
  k_scores_l<<<dim3(48,48), 256, 0, stream>>>(qb, kb, lsum);
  k_fused<0><<<96*16, 256, 0, stream>>>(qb, kb, xbT, lsum, o_R1, o_R2, hpart, nullptr, 0.9f);
  k_fin2<<<NV, 64, 0, stream>>>(hpart, adjs, o_hq2, o_ls);
}

// Round 14
// 240.179 us; speedup vs baseline: 1.4735x; 1.0299x over previous
//
#include <hip/hip_runtime.h>

#define NV 6144
#define DV 64

using short8 = __attribute__((ext_vector_type(8))) short;
using f32x4  = __attribute__((ext_vector_type(4))) float;

static __device__ __forceinline__ unsigned short f2bf(float x){
  unsigned u = __float_as_uint(x);
  u += 0x7FFFu + ((u >> 16) & 1u);      // RNE
  return (unsigned short)(u >> 16);
}
static __device__ __forceinline__ float bf2f(unsigned short u){
  return __uint_as_float(((unsigned)u) << 16);
}

// ---------------- projections: hq = x@Wq (f32 out + bf16 qb), kb = bf16(x@Wk),
// xbT[d][i] = bf16(x@Wa) transposed. Also zeroes lsum + adjs.
template<int FIN>
__global__ __launch_bounds__(256) void k_proj(
    const float* __restrict__ x, const float* __restrict__ Wq,
    const float* __restrict__ Wk, const float* __restrict__ Wa,
    float* __restrict__ hq_out, unsigned short* __restrict__ qb,
    unsigned short* __restrict__ kb, unsigned short* __restrict__ xbT,
    float* __restrict__ lsum, float* __restrict__ adjs)
{
  __shared__ float xr[FIN];
  int i = blockIdx.x, t = threadIdx.x;
  for (int f = t; f < FIN; f += 256) xr[f] = x[(size_t)i*FIN + f];
  if (t == 192) lsum[i] = 0.f;
  if (FIN == 256 && t == 193) adjs[i] = 0.f;
  __syncthreads();
  if (t < 192){
    int w = t >> 6, d = t & 63;
    const float* W = (w == 0) ? Wq : ((w == 1) ? Wk : Wa);
    float acc = 0.f;
    #pragma unroll 8
    for (int f = 0; f < FIN; ++f) acc = fmaf(xr[f], W[f*DV + d], acc);
    size_t o = (size_t)i*DV + d;
    if (w == 0){ hq_out[o] = acc; qb[o] = f2bf(acc); }
    else if (w == 1) kb[o] = f2bf(acc);
    else xbT[(size_t)d*NV + i] = f2bf(acc);
  }
}

// ---------------- phase-2 projection with fused fin1 (sums bf16 hpart[16]):
// x_row = relu(sum_p hpart[p]/deg1) + q1, then 64->64 projections; zeroes lsum.
__global__ __launch_bounds__(256) void k_proj2(
    const unsigned short* __restrict__ hpart, const float* __restrict__ adjs,
    const float* __restrict__ q1, const float* __restrict__ Wq,
    const float* __restrict__ Wk, const float* __restrict__ Wa,
    float* __restrict__ hq_out, unsigned short* __restrict__ qb,
    unsigned short* __restrict__ kb, unsigned short* __restrict__ xbT,
    float* __restrict__ lsum)
{
  __shared__ float xr[64];
  int i = blockIdx.x, t = threadIdx.x;
  const size_t NDK = (size_t)NV*DV;
  if (t < 64){
    float s = 0.f;
    #pragma unroll
    for (int p = 0; p < 16; ++p) s += bf2f(hpart[(size_t)p*NDK + (size_t)i*64 + t]);
    float deg = fmaxf(fmaf(0.8f, adjs[i], 0.2f), 1e-12f);
    xr[t] = fmaxf(s/deg, 0.f) + q1[(size_t)i*64 + t];
  }
  if (t == 192) lsum[i] = 0.f;
  __syncthreads();
  if (t < 192){
    int w = t >> 6, d = t & 63;
    const float* W = (w == 0) ? Wq : ((w == 1) ? Wk : Wa);
    float acc = 0.f;
    #pragma unroll
    for (int f = 0; f < 64; ++f) acc = fmaf(xr[f], W[f*DV + d], acc);
    size_t o = (size_t)i*DV + d;
    if (w == 0){ hq_out[o] = acc; qb[o] = f2bf(acc); }
    else if (w == 1) kb[o] = f2bf(acc);
    else xbT[(size_t)d*NV + i] = f2bf(acc);
  }
}

// ---------------- pass 1: lsum[i] = sum_j exp((qb@kb^T)*0.125)  (no-max softmax)
// grid: (48,48); block 256 = 4 waves (2x2 of 64x64); tile 128x128.
__global__ __launch_bounds__(256) void k_scores_l(
    const unsigned short* __restrict__ qb, const unsigned short* __restrict__ kb,
    float* __restrict__ lsum)
{
  __shared__ unsigned short qs[128][72];   // +8 ushort pad
  __shared__ unsigned short ks[128][72];
  int t = threadIdx.x;
  int row0 = blockIdx.x * 128, col0 = blockIdx.y * 128;
  #pragma unroll
  for (int p = 0; p < 4; ++p){
    int idx = t + p*256;
    int r = idx >> 3, c = (idx & 7) * 8;
    *(uint4*)&qs[r][c] = *(const uint4*)&qb[(size_t)(row0 + r)*DV + c];
    *(uint4*)&ks[r][c] = *(const uint4*)&kb[(size_t)(col0 + r)*DV + c];
  }
  __syncthreads();
  int lane = t & 63, w = t >> 6;
  int wi = (w >> 1) * 64, wj = (w & 1) * 64;
  int m = lane & 15, g = lane >> 4;
  f32x4 acc[4][4];
  #pragma unroll
  for (int r = 0; r < 4; ++r)
    #pragma unroll
    for (int c = 0; c < 4; ++c)
      acc[r][c] = (f32x4){0.f, 0.f, 0.f, 0.f};
  #pragma unroll
  for (int kk = 0; kk < 2; ++kk){
    short8 a[4], b[4];
    #pragma unroll
    for (int r = 0; r < 4; ++r)
      a[r] = *(const short8*)&qs[wi + r*16 + m][kk*32 + g*8];
    #pragma unroll
    for (int c = 0; c < 4; ++c)
      b[c] = *(const short8*)&ks[wj + c*16 + m][kk*32 + g*8];
    #pragma unroll
    for (int r = 0; r < 4; ++r)
      #pragma unroll
      for (int c = 0; c < 4; ++c)
        acc[r][c] = __builtin_amdgcn_mfma_f32_16x16x32_bf16(a[r], b[c], acc[r][c], 0, 0, 0);
  }
  #pragma unroll
  for (int r = 0; r < 4; ++r){
    float rs[4] = {0.f, 0.f, 0.f, 0.f};
    #pragma unroll
    for (int c = 0; c < 4; ++c)
      #pragma unroll
      for (int v = 0; v < 4; ++v)
        rs[v] += __expf(acc[r][c][v] * 0.125f);
    #pragma unroll
    for (int v = 0; v < 4; ++v){
      float s = rs[v];
      s += __shfl_xor(s, 1);
      s += __shfl_xor(s, 2);
      s += __shfl_xor(s, 4);
      s += __shfl_xor(s, 8);
      if (m == 0) atomicAdd(&lsum[row0 + wi + r*16 + g*4 + v], s);
    }
  }
}

// ---------------- pass 2 (fused): recompute S chunk, R = a*base+(1-a)*e/l,
// write R f32 (output), R bf16 -> LDS, agg-MFMA into hpart[split] (bf16).
// grid: 96 row-tiles * 16 k-splits; block 256 = 4 waves; 64 rows x 384 k.
// (round-8/11/13 structure — verified 247-254 us three times; do not restructure)
template<int PHASE1>
__global__ __launch_bounds__(256) void k_fused(
    const unsigned short* __restrict__ qb, const unsigned short* __restrict__ kb,
    const unsigned short* __restrict__ xbT, const float* __restrict__ lsum,
    const float* __restrict__ base, float* __restrict__ Rout,
    unsigned short* __restrict__ hpart, float* __restrict__ adjs, float aconst)
{
  __shared__ unsigned short qs[64][72];    // q rows (persistent)
  __shared__ unsigned short ks[128][72];   // k rows for current chunk
  __shared__ unsigned short rs[64][136];   // R bf16 tile (agg A-operand)
  __shared__ unsigned short xt[64][136];   // xbT chunk (agg B-operand)
  __shared__ float linv[64];

  int t = threadIdx.x;
  int tile = blockIdx.x >> 4, split = blockIdx.x & 15;
  int row0 = tile * 64, k0 = split * 384;
  int lane = t & 63, w = t >> 6;
  int m = lane & 15, g = lane >> 4;

  #pragma unroll
  for (int p = 0; p < 2; ++p){             // qs: 64 rows x 8 uint4
    int idx = t + p*256;
    int r = idx >> 3, c = (idx & 7)*8;
    *(uint4*)&qs[r][c] = *(const uint4*)&qb[(size_t)(row0 + r)*DV + c];
  }
  if (t < 64) linv[t] = (1.0f - aconst) / lsum[row0 + t];

  int srow = (w >> 1) * 32;                // scores wave role
  int scol = (w & 1) * 64;
  float asum[2][4];
  if (PHASE1){
    #pragma unroll
    for (int r = 0; r < 2; ++r)
      #pragma unroll
      for (int v = 0; v < 4; ++v) asum[r][v] = 0.f;
  }
  f32x4 acc_g[4];
  #pragma unroll
  for (int c = 0; c < 4; ++c) acc_g[c] = (f32x4){0.f, 0.f, 0.f, 0.f};

  for (int kc = 0; kc < 3; ++kc){
    int c0 = k0 + kc*128;
    __syncthreads();                       // prev agg reads of ks/xt/rs done
    #pragma unroll
    for (int p = 0; p < 4; ++p){           // ks: 128 rows x 8 uint4
      int idx = t + p*256;
      int r = idx >> 3, c = (idx & 7)*8;
      *(uint4*)&ks[r][c] = *(const uint4*)&kb[(size_t)(c0 + r)*DV + c];
    }
    #pragma unroll
    for (int p = 0; p < 4; ++p){           // xt: 64 d x 16 uint4
      int idx = t + p*256;
      int d = idx >> 4, c = (idx & 15)*8;
      *(uint4*)&xt[d][c] = *(const uint4*)&xbT[(size_t)d*NV + c0 + c];
    }
    __syncthreads();
    // scores MFMA: this wave's 32 rows x 64 cols
    f32x4 acc_s[2][4];
    #pragma unroll
    for (int r = 0; r < 2; ++r)
      #pragma unroll
      for (int c = 0; c < 4; ++c) acc_s[r][c] = (f32x4){0.f, 0.f, 0.f, 0.f};
    #pragma unroll
    for (int kk = 0; kk < 2; ++kk){
      short8 a[2], b[4];
      #pragma unroll
      for (int r = 0; r < 2; ++r)
        a[r] = *(const short8*)&qs[srow + r*16 + m][kk*32 + g*8];
      #pragma unroll
      for (int c = 0; c < 4; ++c)
        b[c] = *(const short8*)&ks[scol + c*16 + m][kk*32 + g*8];
      #pragma unroll
      for (int r = 0; r < 2; ++r)
        #pragma unroll
        for (int c = 0; c < 4; ++c)
          acc_s[r][c] = __builtin_amdgcn_mfma_f32_16x16x32_bf16(a[r], b[c], acc_s[r][c], 0, 0, 0);
    }
    // blend: e, R write (f32 out), rs write (bf16), adjsum partials
    #pragma unroll
    for (int r = 0; r < 2; ++r){
      #pragma unroll
      for (int c = 0; c < 4; ++c){
        int col_l = scol + c*16 + m;
        size_t gcol = (size_t)c0 + col_l;
        #pragma unroll
        for (int v = 0; v < 4; ++v){
          int row_l = srow + r*16 + g*4 + v;
          size_t goff = (size_t)(row0 + row_l)*NV + gcol;
          float e = __expf(acc_s[r][c][v] * 0.125f);
          float bv = base[goff];
          float rv = fmaf(aconst, bv, e * linv[row_l]);
          Rout[goff] = rv;
          rs[row_l][col_l] = f2bf(rv);
          if (PHASE1) asum[r][v] += bv;
        }
      }
    }
    __syncthreads();
    // agg MFMA: wave w owns rows w*16..w*16+15; full d=64
    #pragma unroll
    for (int kk = 0; kk < 4; ++kk){
      short8 a = *(const short8*)&rs[w*16 + m][kk*32 + g*8];
      short8 b[4];
      #pragma unroll
      for (int c = 0; c < 4; ++c)
        b[c] = *(const short8*)&xt[c*16 + m][kk*32 + g*8];
      #pragma unroll
      for (int c = 0; c < 4; ++c)
        acc_g[c] = __builtin_amdgcn_mfma_f32_16x16x32_bf16(a, b[c], acc_g[c], 0, 0, 0);
    }
  }
  // hpart epilogue (deterministic, bf16)
  unsigned short* hp = hpart + (size_t)split * NV * DV;
  #pragma unroll
  for (int c = 0; c < 4; ++c){
    int d = c*16 + m;
    #pragma unroll
    for (int v = 0; v < 4; ++v){
      int row = row0 + w*16 + g*4 + v;
      hp[(size_t)row*DV + d] = f2bf(acc_g[c][v]);
    }
  }
  if (PHASE1){
    #pragma unroll
    for (int r = 0; r < 2; ++r)
      #pragma unroll
      for (int v = 0; v < 4; ++v){
        float s = asum[r][v];
        s += __shfl_xor(s, 1);
        s += __shfl_xor(s, 2);
        s += __shfl_xor(s, 4);
        s += __shfl_xor(s, 8);
        if (m == 0) atomicAdd(&adjs[row0 + srow + r*16 + g*4 + v], s);
      }
  }
}

// ---------------- finalize phase 2: h2 = sum(hpart)/deg2 + q2; log_softmax
__global__ __launch_bounds__(64) void k_fin2(
    const unsigned short* __restrict__ hpart, const float* __restrict__ adjsum,
    const float* __restrict__ q2, float* __restrict__ out0)
{
  int i = blockIdx.x, d = threadIdx.x;
  int idx = i*64 + d;
  float hv = 0.f;
  #pragma unroll
  for (int p = 0; p < 16; ++p) hv += bf2f(hpart[(size_t)p*NV*DV + idx]);
  float deg1 = fmaxf(fmaf(0.8f, adjsum[i], 0.2f), 1e-12f);
  float deg2 = fmaxf(fmaf(0.9f, deg1, 0.1f), 1e-12f);
  float v = hv/deg2 + q2[idx];
  float mm = v;
  #pragma unroll
  for (int mask = 32; mask; mask >>= 1) mm = fmaxf(mm, __shfl_xor(mm, mask));
  float ex = __expf(v - mm);
  #pragma unroll
  for (int mask = 32; mask; mask >>= 1) ex += __shfl_xor(ex, mask);
  out0[idx] = v - mm - __logf(ex);
}

extern "C" void kernel_launch(void* const* d_in, const int* in_sizes, int n_in,
                              void* d_out, int out_size, void* d_ws, size_t ws_size,
                              hipStream_t stream) {
  const float* adj  = (const float*)d_in[0];
  const float* feat = (const float*)d_in[1];
  const float* Wq1  = (const float*)d_in[2];
  const float* Wk1  = (const float*)d_in[3];
  const float* Wa1  = (const float*)d_in[4];
  const float* Wq2  = (const float*)d_in[5];
  const float* Wk2  = (const float*)d_in[6];
  const float* Wa2  = (const float*)d_in[7];

  float* out   = (float*)d_out;
  float* o_ls  = out;                        // [N,64] log_softmax(h2)
  float* o_hq1 = out + (size_t)NV*DV;        // [N,64]
  float* o_R1  = o_hq1 + (size_t)NV*DV;      // [N,N]
  float* o_hq2 = o_R1 + (size_t)NV*NV;       // [N,64]
  float* o_R2  = o_hq2 + (size_t)NV*DV;      // [N,N]

  const size_t ND = (size_t)NV*DV;           // 393216

  // d_ws: lsum, adjs, hpart (bf16), qb, kb, xbT.
  float* Wf   = (float*)d_ws;
  float* lsum = Wf;                          // [N]
  float* adjs = lsum + NV;                   // [N]
  unsigned short* hpart = (unsigned short*)(adjs + NV);    // [16][N][64] bf16
  unsigned short* qb  = hpart + 16*ND;                     // [N,64] bf16
  unsigned short* kb  = qb + ND;                           // [N,64] bf16
  unsigned short* xbT = kb + ND;                           // [64][N] bf16

  // phase 1
  k_proj<256><<<NV, 256, 0, stream>>>(feat, Wq1, Wk1, Wa1, o_hq1, qb, kb, xbT, lsum, adjs);
  k_scores_l<<<dim3(48,48), 256, 0, stream>>>(qb, kb, lsum);
  k_fused<1><<<96*16, 256, 0, stream>>>(qb, kb, xbT, lsum, adj, o_R1, hpart, adjs, 0.8f);
  // phase 2
  k_proj2<<<NV, 256, 0, stream>>>(hpart, adjs, o_hq1, Wq2, Wk2, Wa2, o_hq2, qb, kb, xbT, lsum);
  k_scores_l<<<dim3(48,48), 256, 0, stream>>>(qb, kb, lsum);
  k_fused<0><<<96*16, 256, 0, stream>>>(qb, kb, xbT, lsum, o_R1, o_R2, hpart, nullptr, 0.9f);
  k_fin2<<<NV, 64, 0, stream>>>(hpart, adjs, o_hq2, o_ls);
}